// Round 12
// baseline (670.913 us; speedup 1.0000x reference)
//
#include <hip/hip_runtime.h>

typedef __attribute__((ext_vector_type(8))) short short8;
typedef __attribute__((ext_vector_type(4))) float f32x4;
typedef __attribute__((ext_vector_type(2))) float f32x2;

// ---------- helpers ----------
__device__ __forceinline__ ushort f2bf(float v) {
    unsigned u = __builtin_bit_cast(unsigned, v);
    unsigned r = (u + 0x7FFFu + ((u >> 16) & 1u)) >> 16;
    return (ushort)r;
}
__device__ __forceinline__ float lo16(unsigned p) { return __builtin_bit_cast(float, p << 16); }
__device__ __forceinline__ float hi16(unsigned p) { return __builtin_bit_cast(float, p & 0xFFFF0000u); }

__device__ __forceinline__ float fast_tanh(float x) {
    float cx = fminf(fmaxf(x, -9.f), 9.f);
    float e = __expf(2.f * cx);
    return (e - 1.f) / (e + 1.f);
}

__device__ __forceinline__ void async16(const void* g, void* l) {
    __builtin_amdgcn_global_load_lds(
        (const __attribute__((address_space(1))) unsigned*)g,
        (__attribute__((address_space(3))) unsigned*)l, 16, 0, 0);
}

#define BSHIFT 9          // 512 nodes per bucket
#define CCHUNK 1024       // edges per CSR-build block (4 per thread)

// ---------- CSR build: bucketed counting sort (no per-edge global atomics) ----------
__global__ __launch_bounds__(256) void bucket_count(const int* __restrict__ src,
        const int* __restrict__ dst, int* __restrict__ gbc /*[512]: dst, src*/, int E) {
    __shared__ int cd[4][256];
    __shared__ int cs[4][256];
    int t = threadIdx.x;
    int wv = t >> 6;
    ((int4*)cd)[t] = make_int4(0, 0, 0, 0);
    ((int4*)cs)[t] = make_int4(0, 0, 0, 0);
    __syncthreads();
    int i = blockIdx.x * CCHUNK + t * 4;
    if (i + 3 < E) {
        int4 d = *(const int4*)(dst + i);
        int4 s = *(const int4*)(src + i);
        atomicAdd(&cd[wv][d.x >> BSHIFT], 1);
        atomicAdd(&cd[wv][d.y >> BSHIFT], 1);
        atomicAdd(&cd[wv][d.z >> BSHIFT], 1);
        atomicAdd(&cd[wv][d.w >> BSHIFT], 1);
        atomicAdd(&cs[wv][s.x >> BSHIFT], 1);
        atomicAdd(&cs[wv][s.y >> BSHIFT], 1);
        atomicAdd(&cs[wv][s.z >> BSHIFT], 1);
        atomicAdd(&cs[wv][s.w >> BSHIFT], 1);
    } else {
#pragma unroll
        for (int m = 0; m < 4; ++m) {
            int ii = i + m;
            if (ii < E) {
                atomicAdd(&cd[wv][dst[ii] >> BSHIFT], 1);
                atomicAdd(&cs[wv][src[ii] >> BSHIFT], 1);
            }
        }
    }
    __syncthreads();
    int sd = cd[0][t] + cd[1][t] + cd[2][t] + cd[3][t];
    int ssum = cs[0][t] + cs[1][t] + cs[2][t] + cs[3][t];
    if (sd) atomicAdd(&gbc[t], sd);
    if (ssum) atomicAdd(&gbc[256 + t], ssum);
}

__global__ void scan_buckets(const int* __restrict__ gbc, int* __restrict__ bucketBase,
                             int* __restrict__ pairCursor, int* __restrict__ srcBase,
                             int* __restrict__ srcCursor, int* __restrict__ roff,
                             int N, int E) {
    __shared__ int s[256];
    int t = threadIdx.x;
    int v = gbc[t];
    s[t] = v; __syncthreads();
    for (int o = 1; o < 256; o <<= 1) {
        int y = (t >= o) ? s[t - o] : 0;
        __syncthreads();
        s[t] += y;
        __syncthreads();
    }
    bucketBase[t] = s[t] - v;
    pairCursor[t] = s[t] - v;
    if (t == 255) bucketBase[256] = s[255];
    __syncthreads();
    int v2 = gbc[256 + t];
    s[t] = v2; __syncthreads();
    for (int o = 1; o < 256; o <<= 1) {
        int y = (t >= o) ? s[t - o] : 0;
        __syncthreads();
        s[t] += y;
        __syncthreads();
    }
    srcBase[t] = s[t] - v2;
    srcCursor[t] = s[t] - v2;
    if (t == 255) srcBase[256] = s[255];
    if (t == 0) roff[N] = E;
}

__global__ __launch_bounds__(256) void part_scatter(const int* __restrict__ src,
        const int* __restrict__ dst, int* __restrict__ pairCursor,
        int* __restrict__ srcCursor, uint2* __restrict__ pairs,
        int* __restrict__ sbuf, int E) {
    __shared__ int cntd[256], based[256];
    __shared__ int cnts[256], bases[256];
    int t = threadIdx.x;
    cntd[t] = 0; cnts[t] = 0;
    __syncthreads();
    int i = blockIdx.x * CCHUNK + t * 4;
    int dd[4], sv[4], rkd[4], rks[4];
    if (i + 3 < E) {
        int4 d = *(const int4*)(dst + i);
        int4 s = *(const int4*)(src + i);
        dd[0] = d.x; dd[1] = d.y; dd[2] = d.z; dd[3] = d.w;
        sv[0] = s.x; sv[1] = s.y; sv[2] = s.z; sv[3] = s.w;
    } else {
#pragma unroll
        for (int m = 0; m < 4; ++m) {
            int ii = i + m;
            if (ii < E) { dd[m] = dst[ii]; sv[m] = src[ii]; }
            else        { dd[m] = -1; sv[m] = 0; }
        }
    }
#pragma unroll
    for (int e = 0; e < 4; ++e) {
        if (dd[e] >= 0) {
            rkd[e] = atomicAdd(&cntd[dd[e] >> BSHIFT], 1);
            rks[e] = atomicAdd(&cnts[sv[e] >> BSHIFT], 1);
        }
    }
    __syncthreads();
    based[t] = cntd[t] ? atomicAdd(&pairCursor[t], cntd[t]) : 0;
    bases[t] = cnts[t] ? atomicAdd(&srcCursor[t], cnts[t]) : 0;
    __syncthreads();
#pragma unroll
    for (int e = 0; e < 4; ++e) {
        if (dd[e] >= 0) {
            pairs[based[dd[e] >> BSHIFT] + rkd[e]] = make_uint2((unsigned)sv[e], (unsigned)dd[e]);
            sbuf[bases[sv[e] >> BSHIFT] + rks[e]] = sv[e];
        }
    }
}

// merged: blocks [0,numBuckets) build csr/roff/sIn; blocks [numBuckets,2x) count outdeg->sOut
__global__ __launch_bounds__(1024) void build_all(const uint2* __restrict__ pairs,
        const int* __restrict__ sbuf, const int* __restrict__ bucketBase,
        const int* __restrict__ srcBase, int* __restrict__ roff,
        float* __restrict__ sIn, float* __restrict__ sOut, int* __restrict__ csr,
        int N, int numBuckets) {
    __shared__ int cnt[512];
    __shared__ int cur[512];
    __shared__ int ss[256];
    int b = blockIdx.x;
    int t = threadIdx.x;
    if (b >= numBuckets) {
        // ---- src-count branch ----
        int b2 = b - numBuckets;
        int lo = b2 << BSHIFT;
        int s0 = srcBase[b2], s1 = srcBase[b2 + 1];
        if (t < 512) cnt[t] = 0;
        __syncthreads();
        for (int j = s0 + t; j < s1; j += 1024)
            atomicAdd(&cnt[sbuf[j] - lo], 1);
        __syncthreads();
        if (t < 512) {
            int n0 = lo + t;
            if (n0 < N) { int c = cnt[t]; sOut[n0] = rsqrtf((float)(c > 0 ? c : 1)); }
        }
        return;
    }
    // ---- dst-bucket branch (csr build) ----
    int lo = b << BSHIFT;
    int s0 = bucketBase[b], s1 = bucketBase[b + 1];
    if (t < 512) cnt[t] = 0;
    __syncthreads();
    for (int j = s0 + t; j < s1; j += 1024)
        atomicAdd(&cnt[pairs[j].y - lo], 1);
    __syncthreads();
    int c0 = 0, c1 = 0;
    if (t < 256) { c0 = cnt[2 * t]; c1 = cnt[2 * t + 1]; ss[t] = c0 + c1; }
    __syncthreads();
    for (int o = 1; o < 256; o <<= 1) {
        int y = 0;
        if (t < 256 && t >= o) y = ss[t - o];
        __syncthreads();
        if (t < 256) ss[t] += y;
        __syncthreads();
    }
    if (t < 256) {
        int eb = ss[t] - (c0 + c1);
        int p0 = s0 + eb, p1 = s0 + eb + c0;
        cur[2 * t] = p0; cur[2 * t + 1] = p1;
        int n0 = lo + 2 * t, n1 = n0 + 1;
        if (n0 < N) { roff[n0] = p0; sIn[n0] = rsqrtf((float)(c0 > 0 ? c0 : 1)); }
        if (n1 < N) { roff[n1] = p1; sIn[n1] = rsqrtf((float)(c1 > 0 ? c1 : 1)); }
    }
    __syncthreads();
    for (int j = s0 + t; j < s1; j += 1024) {
        uint2 p = pairs[j];
        int pos = atomicAdd(&cur[p.y - lo], 1);
        csr[pos] = (int)p.x;
    }
}

// ---------- merged weight-convert + prescale ----------
// threads [0, totalP): prescale in_feat*outdeg^-0.5 -> fp8 (128B rows)
// threads [totalP, totalP+262144): convw (fp32 KxN -> bf16 NxK, all 6 fused)
__global__ void convw_prescale(const float* w0, const float* w1, const float* w2,
                               const float* w3, const float* w4, const float* w5,
                               ushort* __restrict__ Wt,
                               const float* __restrict__ x, const float* __restrict__ sOut,
                               unsigned char* __restrict__ o, int totalP) {
    int i = blockIdx.x * 256 + threadIdx.x;
    if (i < totalP) {
        int row = i >> 5;
        float s = sOut[row];
        float4 v = ((const float4*)x)[i];
        int pk = __builtin_amdgcn_cvt_pk_fp8_f32(v.x * s, v.y * s, 0, false);
        pk = __builtin_amdgcn_cvt_pk_fp8_f32(v.z * s, v.w * s, pk, true);
        ((unsigned*)o)[i] = (unsigned)pk;
        return;
    }
    int j = i - totalP;
    if (j >= 262144) return;
    int base, Km, Nm; const float* W;
    if      (j < 32768)  { base = 0;      Km = 128; Nm = 256; W = w0; }
    else if (j < 98304)  { base = 32768;  Km = 256; Nm = 256; W = w1; }
    else if (j < 131072) { base = 98304;  Km = 256; Nm = 128; W = w2; }
    else if (j < 163840) { base = 131072; Km = 128; Nm = 256; W = w3; }
    else if (j < 229376) { base = 163840; Km = 256; Nm = 256; W = w4; }
    else                 { base = 229376; Km = 256; Nm = 128; W = w5; }
    int l = j - base;
    int k = l / Nm, n = l % Nm;
    Wt[base + n * Km + k] = f2bf(W[l]);
}

// ---------- aggregation kernels (one wave per dst row; fp8 inputs) ----------
__global__ __launch_bounds__(256) void agg128f8(const unsigned char* __restrict__ F,
        const int* __restrict__ csr, const int* __restrict__ roff,
        const float* __restrict__ sIn, ushort* __restrict__ out, int N) {
    int w = blockIdx.x * 4 + (threadIdx.x >> 6);
    if (w >= N) return;
    int lane = threadIdx.x & 63;
    int b = roff[w], e = roff[w + 1];
    int deg = e - b;
    int n = deg < 64 ? deg : 64;
    float a0 = 0.f, a1 = 0.f;
    const char* base = (const char*)F + lane * 2;  // 2 fp8 cols per lane
    int voff = 0;
    if (n > 0) voff = csr[b + (lane < n ? lane : n - 1)] << 7;  // 128B rows
    int j = 0;
    for (; j + 16 <= n; j += 16) {
        unsigned p[16];
#pragma unroll
        for (int k = 0; k < 16; ++k) {
            int o = __shfl(voff, j + k, 64);
            p[k] = *(const ushort*)(base + (size_t)(unsigned)o);
        }
#pragma unroll
        for (int k = 0; k < 16; ++k) {
            f32x2 d = __builtin_amdgcn_cvt_pk_f32_fp8(p[k], false);
            a0 += d.x; a1 += d.y;
        }
    }
    for (; j + 8 <= n; j += 8) {
        unsigned p[8];
#pragma unroll
        for (int k = 0; k < 8; ++k) {
            int o = __shfl(voff, j + k, 64);
            p[k] = *(const ushort*)(base + (size_t)(unsigned)o);
        }
#pragma unroll
        for (int k = 0; k < 8; ++k) {
            f32x2 d = __builtin_amdgcn_cvt_pk_f32_fp8(p[k], false);
            a0 += d.x; a1 += d.y;
        }
    }
    for (; j < n; ++j) {
        int o = __shfl(voff, j, 64);
        unsigned p = *(const ushort*)(base + (size_t)(unsigned)o);
        f32x2 d = __builtin_amdgcn_cvt_pk_f32_fp8(p, false);
        a0 += d.x; a1 += d.y;
    }
    for (int i = b + 64; i < e; ++i) {
        unsigned p = *(const ushort*)(base + ((size_t)csr[i] << 7));
        f32x2 d = __builtin_amdgcn_cvt_pk_f32_fp8(p, false);
        a0 += d.x; a1 += d.y;
    }
    float s = sIn[w];
    ushort2 o2; o2.x = f2bf(a0 * s); o2.y = f2bf(a1 * s);
    *(ushort2*)(out + (size_t)w * 128 + lane * 2) = o2;
}

__global__ __launch_bounds__(256) void agg256f8(const unsigned char* __restrict__ F,
        const int* __restrict__ csr, const int* __restrict__ roff,
        const float* __restrict__ sIn, ushort* __restrict__ out, int N) {
    int w = blockIdx.x * 4 + (threadIdx.x >> 6);
    if (w >= N) return;
    int lane = threadIdx.x & 63;
    int b = roff[w], e = roff[w + 1];
    int deg = e - b;
    int n = deg < 64 ? deg : 64;
    float a0 = 0.f, a1 = 0.f, a2 = 0.f, a3 = 0.f;
    const char* base = (const char*)F + lane * 4;  // 4 fp8 cols per lane
    int voff = 0;
    if (n > 0) voff = csr[b + (lane < n ? lane : n - 1)] << 8; // 256B rows
    int j = 0;
    for (; j + 16 <= n; j += 16) {
        unsigned p[16];
#pragma unroll
        for (int k = 0; k < 16; ++k) {
            int o = __shfl(voff, j + k, 64);
            p[k] = *(const unsigned*)(base + (size_t)(unsigned)o);
        }
#pragma unroll
        for (int k = 0; k < 16; ++k) {
            f32x2 lo = __builtin_amdgcn_cvt_pk_f32_fp8(p[k], false);
            f32x2 hi = __builtin_amdgcn_cvt_pk_f32_fp8(p[k], true);
            a0 += lo.x; a1 += lo.y; a2 += hi.x; a3 += hi.y;
        }
    }
    for (; j + 8 <= n; j += 8) {
        unsigned p[8];
#pragma unroll
        for (int k = 0; k < 8; ++k) {
            int o = __shfl(voff, j + k, 64);
            p[k] = *(const unsigned*)(base + (size_t)(unsigned)o);
        }
#pragma unroll
        for (int k = 0; k < 8; ++k) {
            f32x2 lo = __builtin_amdgcn_cvt_pk_f32_fp8(p[k], false);
            f32x2 hi = __builtin_amdgcn_cvt_pk_f32_fp8(p[k], true);
            a0 += lo.x; a1 += lo.y; a2 += hi.x; a3 += hi.y;
        }
    }
    for (; j < n; ++j) {
        int o = __shfl(voff, j, 64);
        unsigned p = *(const unsigned*)(base + (size_t)(unsigned)o);
        f32x2 lo = __builtin_amdgcn_cvt_pk_f32_fp8(p, false);
        f32x2 hi = __builtin_amdgcn_cvt_pk_f32_fp8(p, true);
        a0 += lo.x; a1 += lo.y; a2 += hi.x; a3 += hi.y;
    }
    for (int i = b + 64; i < e; ++i) {
        unsigned p = *(const unsigned*)(base + ((size_t)csr[i] << 8));
        f32x2 lo = __builtin_amdgcn_cvt_pk_f32_fp8(p, false);
        f32x2 hi = __builtin_amdgcn_cvt_pk_f32_fp8(p, true);
        a0 += lo.x; a1 += lo.y; a2 += hi.x; a3 += hi.y;
    }
    float s = sIn[w];
    ushort4 o4;
    o4.x = f2bf(a0 * s); o4.y = f2bf(a1 * s);
    o4.z = f2bf(a2 * s); o4.w = f2bf(a3 * s);
    *(ushort4*)(out + (size_t)w * 256 + lane * 4) = o4;
}

__global__ __launch_bounds__(256) void agg_softmax_f8(const unsigned char* __restrict__ F,
        const int* __restrict__ csr, const int* __restrict__ roff,
        const float* __restrict__ sIn, const float* __restrict__ bias,
        float* __restrict__ outh, ushort* __restrict__ outb, int N) {
    int w = blockIdx.x * 4 + (threadIdx.x >> 6);
    if (w >= N) return;
    int lane = threadIdx.x & 63;
    int b = roff[w], e = roff[w + 1];
    int deg = e - b;
    int n = deg < 64 ? deg : 64;
    float a0 = 0.f, a1 = 0.f;
    const char* base = (const char*)F + lane * 2;
    int voff = 0;
    if (n > 0) voff = csr[b + (lane < n ? lane : n - 1)] << 7;  // 128B rows
    int j = 0;
    for (; j + 16 <= n; j += 16) {
        unsigned p[16];
#pragma unroll
        for (int k = 0; k < 16; ++k) {
            int o = __shfl(voff, j + k, 64);
            p[k] = *(const ushort*)(base + (size_t)(unsigned)o);
        }
#pragma unroll
        for (int k = 0; k < 16; ++k) {
            f32x2 d = __builtin_amdgcn_cvt_pk_f32_fp8(p[k], false);
            a0 += d.x; a1 += d.y;
        }
    }
    for (; j + 8 <= n; j += 8) {
        unsigned p[8];
#pragma unroll
        for (int k = 0; k < 8; ++k) {
            int o = __shfl(voff, j + k, 64);
            p[k] = *(const ushort*)(base + (size_t)(unsigned)o);
        }
#pragma unroll
        for (int k = 0; k < 8; ++k) {
            f32x2 d = __builtin_amdgcn_cvt_pk_f32_fp8(p[k], false);
            a0 += d.x; a1 += d.y;
        }
    }
    for (; j < n; ++j) {
        int o = __shfl(voff, j, 64);
        unsigned p = *(const ushort*)(base + (size_t)(unsigned)o);
        f32x2 d = __builtin_amdgcn_cvt_pk_f32_fp8(p, false);
        a0 += d.x; a1 += d.y;
    }
    for (int i = b + 64; i < e; ++i) {
        unsigned p = *(const ushort*)(base + ((size_t)csr[i] << 7));
        f32x2 d = __builtin_amdgcn_cvt_pk_f32_fp8(p, false);
        a0 += d.x; a1 += d.y;
    }
    float s = sIn[w];
    float2 bb = *(const float2*)(bias + lane * 2);
    float l0 = a0 * s + bb.x, l1 = a1 * s + bb.y;
    float m = fmaxf(l0, l1);
    for (int o = 32; o; o >>= 1) m = fmaxf(m, __shfl_xor(m, o, 64));
    float e0 = __expf(l0 - m), e1 = __expf(l1 - m);
    float sm = e0 + e1;
    for (int o = 32; o; o >>= 1) sm += __shfl_xor(sm, o, 64);
    float inv = 1.f / sm;
    float r0 = e0 * inv, r1 = e1 * inv;
    float2 fo; fo.x = r0; fo.y = r1;
    *(float2*)(outh + (size_t)w * 128 + lane * 2) = fo;
    ushort2 o2; o2.x = f2bf(r0); o2.y = f2bf(r1);
    *(ushort2*)(outb + (size_t)w * 128 + lane * 2) = o2;
}

// ---------- GEMM v3: conflict-free [slot][col] LDS layout, 8 waves ----------
// MODE 0: tanh(acc+bias)*(rowscale?:1) -> bf16 | 1: acc -> bf16
// MODE 3: row_softmax(acc+bias) -> fp32 (Nn==128) | 4: tanh*rowscale -> fp8 | 5: acc -> fp8
template <int MODE, int K>
__global__ __launch_bounds__(512, 4) void gemm3(
        const ushort* __restrict__ A, const ushort* __restrict__ Wt,
        const float* __restrict__ bias, const float* __restrict__ rowscale,
        void* __restrict__ out, int M, int Nn) {
    constexpr int KS = K / 32;          // mfma K-steps (= staged chunks per wave)
    __shared__ ushort ldsW[(K / 8) * 1024];   // K/8 slots x 128 cols x 16B

    const int tid = threadIdx.x;
    const int lane = tid & 63;
    const int wid = tid >> 6;           // 0..7
    const int nby = Nn >> 7;
    const int bx = (int)blockIdx.x / nby;
    const int by = (int)blockIdx.x - bx * nby;
    const int rowbase = bx * 128;
    const int colbase = by * 128;

    // stage: chunk c (1KB) = slot s=c>>1, col half h=c&1; lane covers col h*64+lane
#pragma unroll
    for (int it = 0; it < KS; ++it) {
        int c = wid * KS + it;
        int s = c >> 1, h = c & 1;
        async16(Wt + (size_t)(colbase + h * 64 + lane) * K + s * 8,
                (char*)ldsW + c * 1024);
    }

    // A fragments direct from global (wave's 16 rows; 64B/row per ks step)
    const int l15 = lane & 15, l4 = lane >> 4;
    short8 a[KS];
    {
        int grow = rowbase + wid * 16 + l15;
        if (grow > M - 1) grow = M - 1;
        const ushort* ap = A + (size_t)grow * K + l4 * 8;
#pragma unroll
        for (int ks = 0; ks < KS; ++ks)
            a[ks] = *(const short8*)(ap + ks * 32);
    }

    f32x4 acc[8];
#pragma unroll
    for (int j = 0; j < 8; ++j) acc[j] = (f32x4){0.f, 0.f, 0.f, 0.f};

    __syncthreads();

#pragma unroll
    for (int ks = 0; ks < KS; ++ks) {
        const ushort* bp = &ldsW[(ks * 4 + l4) * 1024 + l15 * 8];
#pragma unroll
        for (int ct = 0; ct < 8; ++ct) {
            short8 b = *(const short8*)(bp + ct * 128);
            acc[ct] = __builtin_amdgcn_mfma_f32_16x16x32_bf16(a[ks], b, acc[ct], 0, 0, 0);
        }
    }

    // epilogue (wave owns rows rowbase+wid*16 .. +15, cols colbase .. +127)
    float bv[8];
#pragma unroll
    for (int ct = 0; ct < 8; ++ct)
        bv[ct] = (MODE != 1 && MODE != 5 && bias) ? bias[colbase + ct * 16 + l15] : 0.f;

    if (MODE == 4 || MODE == 5) {
#pragma unroll
        for (int rg = 0; rg < 4; ++rg) {
            int row = rowbase + wid * 16 + l4 * 4 + rg;
            if (row >= M) continue;            // row uniform over shfl pair
            float sc = (MODE == 4 && rowscale) ? rowscale[row] : 1.f;
#pragma unroll
            for (int ct = 0; ct < 8; ++ct) {
                float v = acc[ct][rg] + bv[ct];
                if (MODE == 4) v = fast_tanh(v) * sc;
                float vp = __shfl_xor(v, 1, 64);   // partner col (l15^1)
                if ((l15 & 1) == 0) {
                    int pk = __builtin_amdgcn_cvt_pk_fp8_f32(v, vp, 0, false);
                    *(ushort*)((char*)out + (size_t)row * Nn + colbase + ct * 16 + l15)
                        = (ushort)(pk & 0xFFFF);
                }
            }
        }
    } else if (MODE != 3) {
#pragma unroll
        for (int rg = 0; rg < 4; ++rg) {
            int row = rowbase + wid * 16 + l4 * 4 + rg;
            if (row >= M) continue;
            float sc = 1.f;
            if (MODE == 0 && rowscale) sc = rowscale[row];
#pragma unroll
            for (int ct = 0; ct < 8; ++ct) {
                int col = colbase + ct * 16 + l15;
                float v = acc[ct][rg] + bv[ct];
                if (MODE == 0) v = fast_tanh(v) * sc;
                ((ushort*)out)[(size_t)row * Nn + col] = f2bf(v);
            }
        }
    } else {
        // wave-local row softmax (row's 128 cols live in 16 lanes x 8 ct)
#pragma unroll
        for (int rg = 0; rg < 4; ++rg) {
            int row = rowbase + wid * 16 + l4 * 4 + rg;
            float m = acc[0][rg] + bv[0];
#pragma unroll
            for (int ct = 1; ct < 8; ++ct) m = fmaxf(m, acc[ct][rg] + bv[ct]);
            m = fmaxf(m, __shfl_xor(m, 1, 64));
            m = fmaxf(m, __shfl_xor(m, 2, 64));
            m = fmaxf(m, __shfl_xor(m, 4, 64));
            m = fmaxf(m, __shfl_xor(m, 8, 64));
            float ev[8], s = 0.f;
#pragma unroll
            for (int ct = 0; ct < 8; ++ct) {
                ev[ct] = __expf(acc[ct][rg] + bv[ct] - m);
                s += ev[ct];
            }
            s += __shfl_xor(s, 1, 64);
            s += __shfl_xor(s, 2, 64);
            s += __shfl_xor(s, 4, 64);
            s += __shfl_xor(s, 8, 64);
            float inv = 1.f / s;
            if (row < M) {
#pragma unroll
                for (int ct = 0; ct < 8; ++ct) {
                    int col = colbase + ct * 16 + l15;
                    ((float*)out)[(size_t)row * Nn + col] = ev[ct] * inv;
                }
            }
        }
    }
}

// ---------- launch ----------
extern "C" void kernel_launch(void* const* d_in, const int* in_sizes, int n_in,
                              void* d_out, int out_size, void* d_ws, size_t ws_size,
                              hipStream_t stream) {
    (void)n_in; (void)out_size; (void)ws_size;
    const float* in_feat = (const float*)d_in[0];
    const int*   src     = (const int*)d_in[1];
    const int*   dstp    = (const int*)d_in[2];
    const float* Wc0 = (const float*)d_in[3];  const float* bc0 = (const float*)d_in[4];
    const float* Wc1 = (const float*)d_in[5];  const float* bc1 = (const float*)d_in[6];
    const float* Wc2 = (const float*)d_in[7];  const float* bc2 = (const float*)d_in[8];
    const float* Wr0 = (const float*)d_in[9];  const float* br0 = (const float*)d_in[10];
    const float* Wr1 = (const float*)d_in[11]; const float* br1 = (const float*)d_in[12];
    const float* Wr2 = (const float*)d_in[13]; const float* br2 = (const float*)d_in[14];

    const int N = in_sizes[0] / 128;
    const int E = in_sizes[1];
    const int numBuckets = (N + ((1 << BSHIFT) - 1)) >> BSHIFT;

    char* ws = (char*)d_ws;
    size_t off = 0;
    auto alloc = [&](size_t bytes) -> char* {
        char* p = ws + off;
        off += (bytes + 255) & ~(size_t)255;
        return p;
    };
    char* S1 = alloc((size_t)N * 256 * 2);
    char* S2 = alloc((size_t)N * 256 * 2);
    int* csr    = (int*)alloc((size_t)E * 4);
    int* roff   = (int*)alloc((size_t)(N + 1) * 4);
    int* sbuf   = (int*)alloc((size_t)E * 4);
    float* sOut = (float*)alloc((size_t)N * 4);
    float* sIn  = (float*)alloc((size_t)N * 4);
    ushort* Wt  = (ushort*)alloc(262144 * 2);
    int* gbc        = (int*)alloc(512 * 4);
    int* bucketBase = (int*)alloc(257 * 4);
    int* pairCursor = (int*)alloc(256 * 4);
    int* srcBase    = (int*)alloc(257 * 4);
    int* srcCursor  = (int*)alloc(256 * 4);
    uint2* pairs = (uint2*)S2;

    hipMemsetAsync(gbc, 0, 512 * 4, stream);

    int nblk = (E + CCHUNK - 1) / CCHUNK;
    bucket_count<<<nblk, 256, 0, stream>>>(src, dstp, gbc, E);
    scan_buckets<<<1, 256, 0, stream>>>(gbc, bucketBase, pairCursor, srcBase, srcCursor,
                                        roff, N, E);
    part_scatter<<<nblk, 256, 0, stream>>>(src, dstp, pairCursor, srcCursor, pairs, sbuf, E);
    build_all<<<numBuckets * 2, 1024, 0, stream>>>(pairs, sbuf, bucketBase, srcBase,
                                                   roff, sIn, sOut, csr, N, numBuckets);

    // merged convw + prescale (prescale needs sOut)
    unsigned char* Xf8 = (unsigned char*)S1;
    int totalP = N * 32;
    int cpBlocks = (totalP + 262144 + 255) / 256;
    convw_prescale<<<cpBlocks, 256, 0, stream>>>(Wc0, Wc1, Wc2, Wr0, Wr1, Wr2, Wt,
                                                 in_feat, sOut, Xf8, totalP);

    int aggGrid = (N + 3) / 4;
    int nrb = (N + 127) / 128;   // row blocks

    ushort* A0 = (ushort*)S2;
    agg128f8<<<aggGrid, 256, 0, stream>>>(Xf8, csr, roff, sIn, A0, N);
    // conv1 activation -> fp8 (256B rows) for the heavy gather
    unsigned char* B1f8 = (unsigned char*)S1;
    gemm3<4, 128><<<nrb * 2, 512, 0, stream>>>(A0, Wt, bc0, sOut, B1f8, N, 256);
    ushort* A1 = (ushort*)S2;
    agg256f8<<<aggGrid, 256, 0, stream>>>(B1f8, csr, roff, sIn, A1, N);
    ushort* B2 = (ushort*)S1;
    gemm3<0, 256><<<nrb * 2, 512, 0, stream>>>(A1, Wt + 32768, bc1, sOut, B2, N, 256);
    // conv3 pre-agg logits -> fp8 (128B rows)
    unsigned char* T3f8 = (unsigned char*)S2;
    gemm3<5, 256><<<nrb, 512, 0, stream>>>(B2, Wt + 98304, nullptr, nullptr, T3f8, N, 128);
    float* outh = (float*)d_out;
    ushort* Hbf = (ushort*)S1;
    agg_softmax_f8<<<aggGrid, 256, 0, stream>>>(T3f8, csr, roff, sIn, bc2, outh, Hbf, N);
    ushort* R1 = (ushort*)S2;
    gemm3<0, 128><<<nrb * 2, 512, 0, stream>>>(Hbf, Wt + 131072, br0, nullptr, R1, N, 256);
    ushort* R2 = (ushort*)S1;
    gemm3<0, 256><<<nrb * 2, 512, 0, stream>>>(R1, Wt + 163840, br1, nullptr, R2, N, 256);
    gemm3<3, 256><<<nrb, 512, 0, stream>>>(R2, Wt + 229376, br2, nullptr,
                                           outh + (size_t)N * 128, N, 128);
}

// Round 13
// 641.915 us; speedup vs baseline: 1.0452x; 1.0452x over previous
//
#include <hip/hip_runtime.h>

typedef __attribute__((ext_vector_type(8))) short short8;
typedef __attribute__((ext_vector_type(4))) float f32x4;
typedef __attribute__((ext_vector_type(2))) float f32x2;

// ---------- helpers ----------
__device__ __forceinline__ ushort f2bf(float v) {
    unsigned u = __builtin_bit_cast(unsigned, v);
    unsigned r = (u + 0x7FFFu + ((u >> 16) & 1u)) >> 16;
    return (ushort)r;
}
__device__ __forceinline__ float lo16(unsigned p) { return __builtin_bit_cast(float, p << 16); }
__device__ __forceinline__ float hi16(unsigned p) { return __builtin_bit_cast(float, p & 0xFFFF0000u); }

__device__ __forceinline__ float fast_tanh(float x) {
    float cx = fminf(fmaxf(x, -9.f), 9.f);
    float e = __expf(2.f * cx);
    return (e - 1.f) / (e + 1.f);
}

__device__ __forceinline__ void async16(const void* g, void* l) {
    __builtin_amdgcn_global_load_lds(
        (const __attribute__((address_space(1))) unsigned*)g,
        (__attribute__((address_space(3))) unsigned*)l, 16, 0, 0);
}

#define BSHIFT 9          // 512 nodes per bucket
#define CCHUNK 2048       // edges per CSR-build block

// ---------- CSR build: bucketed counting sort (no per-edge global atomics) ----------
__global__ __launch_bounds__(256) void bucket_count(const int* __restrict__ src,
        const int* __restrict__ dst, int* __restrict__ gbc /*[512]: dst, src*/, int E) {
    __shared__ int cd[4][256];
    __shared__ int cs[4][256];
    int t = threadIdx.x;
    int wv = t >> 6;
    ((int4*)cd)[t] = make_int4(0, 0, 0, 0);
    ((int4*)cs)[t] = make_int4(0, 0, 0, 0);
    __syncthreads();
    int start = blockIdx.x * CCHUNK;
#pragma unroll
    for (int k = 0; k < 2; ++k) {
        int i = start + (k * 256 + t) * 4;
        if (i + 3 < E) {
            int4 d = *(const int4*)(dst + i);
            int4 s = *(const int4*)(src + i);
            atomicAdd(&cd[wv][d.x >> BSHIFT], 1);
            atomicAdd(&cd[wv][d.y >> BSHIFT], 1);
            atomicAdd(&cd[wv][d.z >> BSHIFT], 1);
            atomicAdd(&cd[wv][d.w >> BSHIFT], 1);
            atomicAdd(&cs[wv][s.x >> BSHIFT], 1);
            atomicAdd(&cs[wv][s.y >> BSHIFT], 1);
            atomicAdd(&cs[wv][s.z >> BSHIFT], 1);
            atomicAdd(&cs[wv][s.w >> BSHIFT], 1);
        } else {
#pragma unroll
            for (int m = 0; m < 4; ++m) {
                int ii = i + m;
                if (ii < E) {
                    atomicAdd(&cd[wv][dst[ii] >> BSHIFT], 1);
                    atomicAdd(&cs[wv][src[ii] >> BSHIFT], 1);
                }
            }
        }
    }
    __syncthreads();
    int sd = cd[0][t] + cd[1][t] + cd[2][t] + cd[3][t];
    int ssum = cs[0][t] + cs[1][t] + cs[2][t] + cs[3][t];
    if (sd) atomicAdd(&gbc[t], sd);
    if (ssum) atomicAdd(&gbc[256 + t], ssum);
}

__global__ void scan_buckets(const int* __restrict__ gbc, int* __restrict__ bucketBase,
                             int* __restrict__ pairCursor, int* __restrict__ srcBase,
                             int* __restrict__ srcCursor, int* __restrict__ roff,
                             int N, int E) {
    __shared__ int s[256];
    int t = threadIdx.x;
    int v = gbc[t];
    s[t] = v; __syncthreads();
    for (int o = 1; o < 256; o <<= 1) {
        int y = (t >= o) ? s[t - o] : 0;
        __syncthreads();
        s[t] += y;
        __syncthreads();
    }
    bucketBase[t] = s[t] - v;
    pairCursor[t] = s[t] - v;
    if (t == 255) bucketBase[256] = s[255];
    __syncthreads();
    int v2 = gbc[256 + t];
    s[t] = v2; __syncthreads();
    for (int o = 1; o < 256; o <<= 1) {
        int y = (t >= o) ? s[t - o] : 0;
        __syncthreads();
        s[t] += y;
        __syncthreads();
    }
    srcBase[t] = s[t] - v2;
    srcCursor[t] = s[t] - v2;
    if (t == 255) srcBase[256] = s[255];
    if (t == 0) roff[N] = E;
}

__global__ __launch_bounds__(256) void part_scatter(const int* __restrict__ src,
        const int* __restrict__ dst, int* __restrict__ pairCursor,
        int* __restrict__ srcCursor, uint2* __restrict__ pairs,
        int* __restrict__ sbuf, int E) {
    __shared__ int cntd[256], based[256];
    __shared__ int cnts[256], bases[256];
    int t = threadIdx.x;
    cntd[t] = 0; cnts[t] = 0;
    __syncthreads();
    int start = blockIdx.x * CCHUNK;
    int dd[8], sv[8], rkd[8], rks[8];
#pragma unroll
    for (int k = 0; k < 2; ++k) {
        int i = start + (k * 256 + t) * 4;
        if (i + 3 < E) {
            int4 d = *(const int4*)(dst + i);
            int4 s = *(const int4*)(src + i);
            dd[4 * k + 0] = d.x; dd[4 * k + 1] = d.y; dd[4 * k + 2] = d.z; dd[4 * k + 3] = d.w;
            sv[4 * k + 0] = s.x; sv[4 * k + 1] = s.y; sv[4 * k + 2] = s.z; sv[4 * k + 3] = s.w;
        } else {
#pragma unroll
            for (int m = 0; m < 4; ++m) {
                int ii = i + m;
                if (ii < E) { dd[4 * k + m] = dst[ii]; sv[4 * k + m] = src[ii]; }
                else        { dd[4 * k + m] = -1; sv[4 * k + m] = 0; }
            }
        }
    }
#pragma unroll
    for (int e = 0; e < 8; ++e) {
        if (dd[e] >= 0) {
            rkd[e] = atomicAdd(&cntd[dd[e] >> BSHIFT], 1);
            rks[e] = atomicAdd(&cnts[sv[e] >> BSHIFT], 1);
        }
    }
    __syncthreads();
    based[t] = cntd[t] ? atomicAdd(&pairCursor[t], cntd[t]) : 0;
    bases[t] = cnts[t] ? atomicAdd(&srcCursor[t], cnts[t]) : 0;
    __syncthreads();
#pragma unroll
    for (int e = 0; e < 8; ++e) {
        if (dd[e] >= 0) {
            pairs[based[dd[e] >> BSHIFT] + rkd[e]] = make_uint2((unsigned)sv[e], (unsigned)dd[e]);
            sbuf[bases[sv[e] >> BSHIFT] + rks[e]] = sv[e];
        }
    }
}

__global__ __launch_bounds__(256) void src_count(const int* __restrict__ sbuf,
        const int* __restrict__ srcBase, float* __restrict__ sOut, int N) {
    __shared__ int cnt[512];
    int b = blockIdx.x;
    int t = threadIdx.x;
    int lo = b << BSHIFT;
    int s0 = srcBase[b], s1 = srcBase[b + 1];
    cnt[t] = 0; cnt[t + 256] = 0;
    __syncthreads();
    for (int j = s0 + t; j < s1; j += 256)
        atomicAdd(&cnt[sbuf[j] - lo], 1);
    __syncthreads();
    int n0 = lo + 2 * t, n1 = n0 + 1;
    if (n0 < N) { int c = cnt[2 * t];     sOut[n0] = rsqrtf((float)(c > 0 ? c : 1)); }
    if (n1 < N) { int c = cnt[2 * t + 1]; sOut[n1] = rsqrtf((float)(c > 0 ? c : 1)); }
}

__global__ __launch_bounds__(1024) void build_bucket(const uint2* __restrict__ pairs,
        const int* __restrict__ bucketBase, int* __restrict__ roff,
        float* __restrict__ sIn, int* __restrict__ csr, int N) {
    __shared__ int cnt[512];
    __shared__ int cur[512];
    __shared__ int ss[256];
    int b = blockIdx.x;
    int t = threadIdx.x;
    int lo = b << BSHIFT;
    int s0 = bucketBase[b], s1 = bucketBase[b + 1];
    if (t < 512) cnt[t] = 0;
    __syncthreads();
    for (int j = s0 + t; j < s1; j += 1024)
        atomicAdd(&cnt[pairs[j].y - lo], 1);
    __syncthreads();
    int c0 = 0, c1 = 0;
    if (t < 256) { c0 = cnt[2 * t]; c1 = cnt[2 * t + 1]; ss[t] = c0 + c1; }
    __syncthreads();
    for (int o = 1; o < 256; o <<= 1) {
        int y = 0;
        if (t < 256 && t >= o) y = ss[t - o];
        __syncthreads();
        if (t < 256) ss[t] += y;
        __syncthreads();
    }
    if (t < 256) {
        int eb = ss[t] - (c0 + c1);
        int p0 = s0 + eb, p1 = s0 + eb + c0;
        cur[2 * t] = p0; cur[2 * t + 1] = p1;
        int n0 = lo + 2 * t, n1 = n0 + 1;
        if (n0 < N) { roff[n0] = p0; sIn[n0] = rsqrtf((float)(c0 > 0 ? c0 : 1)); }
        if (n1 < N) { roff[n1] = p1; sIn[n1] = rsqrtf((float)(c1 > 0 ? c1 : 1)); }
    }
    __syncthreads();
    for (int j = s0 + t; j < s1; j += 1024) {
        uint2 p = pairs[j];
        int pos = atomicAdd(&cur[p.y - lo], 1);
        csr[pos] = (int)p.x;
    }
}

// ---------- weight convert + transpose ----------
__global__ void convw(const float* w0, const float* w1, const float* w2,
                      const float* w3, const float* w4, const float* w5,
                      ushort* __restrict__ Wt) {
    int i = blockIdx.x * 256 + threadIdx.x; // < 262144
    int base, Km, Nm; const float* W;
    if      (i < 32768)  { base = 0;      Km = 128; Nm = 256; W = w0; }
    else if (i < 98304)  { base = 32768;  Km = 256; Nm = 256; W = w1; }
    else if (i < 131072) { base = 98304;  Km = 256; Nm = 128; W = w2; }
    else if (i < 163840) { base = 131072; Km = 128; Nm = 256; W = w3; }
    else if (i < 229376) { base = 163840; Km = 256; Nm = 256; W = w4; }
    else                 { base = 229376; Km = 256; Nm = 128; W = w5; }
    int l = i - base;
    int k = l / Nm, n = l % Nm;
    Wt[base + n * Km + k] = f2bf(W[l]);
}

// ---------- prescale: in_feat * outdeg^-0.5 -> fp8 e4m3 (128B rows) ----------
__global__ void prescale(const float* __restrict__ x, const float* __restrict__ sOut,
                         unsigned char* __restrict__ o, int total /* N*32 */) {
    int i = blockIdx.x * 256 + threadIdx.x;
    if (i >= total) return;
    int row = i >> 5;
    float s = sOut[row];
    float4 v = ((const float4*)x)[i];
    int pk = __builtin_amdgcn_cvt_pk_fp8_f32(v.x * s, v.y * s, 0, false);
    pk = __builtin_amdgcn_cvt_pk_fp8_f32(v.z * s, v.w * s, pk, true);
    ((unsigned*)o)[i] = (unsigned)pk;
}

// ---------- aggregation kernels (one wave per dst row; fp8 inputs) ----------
__global__ __launch_bounds__(256) void agg128f8(const unsigned char* __restrict__ F,
        const int* __restrict__ csr, const int* __restrict__ roff,
        const float* __restrict__ sIn, ushort* __restrict__ out, int N) {
    int w = blockIdx.x * 4 + (threadIdx.x >> 6);
    if (w >= N) return;
    int lane = threadIdx.x & 63;
    int b = roff[w], e = roff[w + 1];
    int deg = e - b;
    int n = deg < 64 ? deg : 64;
    float a0 = 0.f, a1 = 0.f;
    const char* base = (const char*)F + lane * 2;  // 2 fp8 cols per lane
    int voff = 0;
    if (n > 0) voff = csr[b + (lane < n ? lane : n - 1)] << 7;  // 128B rows
    int j = 0;
    for (; j + 16 <= n; j += 16) {
        unsigned p[16];
#pragma unroll
        for (int k = 0; k < 16; ++k) {
            int o = __shfl(voff, j + k, 64);
            p[k] = *(const ushort*)(base + (size_t)(unsigned)o);
        }
#pragma unroll
        for (int k = 0; k < 16; ++k) {
            f32x2 d = __builtin_amdgcn_cvt_pk_f32_fp8(p[k], false);
            a0 += d.x; a1 += d.y;
        }
    }
    for (; j + 8 <= n; j += 8) {
        unsigned p[8];
#pragma unroll
        for (int k = 0; k < 8; ++k) {
            int o = __shfl(voff, j + k, 64);
            p[k] = *(const ushort*)(base + (size_t)(unsigned)o);
        }
#pragma unroll
        for (int k = 0; k < 8; ++k) {
            f32x2 d = __builtin_amdgcn_cvt_pk_f32_fp8(p[k], false);
            a0 += d.x; a1 += d.y;
        }
    }
    for (; j < n; ++j) {
        int o = __shfl(voff, j, 64);
        unsigned p = *(const ushort*)(base + (size_t)(unsigned)o);
        f32x2 d = __builtin_amdgcn_cvt_pk_f32_fp8(p, false);
        a0 += d.x; a1 += d.y;
    }
    for (int i = b + 64; i < e; ++i) {
        unsigned p = *(const ushort*)(base + ((size_t)csr[i] << 7));
        f32x2 d = __builtin_amdgcn_cvt_pk_f32_fp8(p, false);
        a0 += d.x; a1 += d.y;
    }
    float s = sIn[w];
    ushort2 o2; o2.x = f2bf(a0 * s); o2.y = f2bf(a1 * s);
    *(ushort2*)(out + (size_t)w * 128 + lane * 2) = o2;
}

__global__ __launch_bounds__(256) void agg256f8(const unsigned char* __restrict__ F,
        const int* __restrict__ csr, const int* __restrict__ roff,
        const float* __restrict__ sIn, ushort* __restrict__ out, int N) {
    int w = blockIdx.x * 4 + (threadIdx.x >> 6);
    if (w >= N) return;
    int lane = threadIdx.x & 63;
    int b = roff[w], e = roff[w + 1];
    int deg = e - b;
    int n = deg < 64 ? deg : 64;
    float a0 = 0.f, a1 = 0.f, a2 = 0.f, a3 = 0.f;
    const char* base = (const char*)F + lane * 4;  // 4 fp8 cols per lane
    int voff = 0;
    if (n > 0) voff = csr[b + (lane < n ? lane : n - 1)] << 8; // 256B rows
    int j = 0;
    for (; j + 16 <= n; j += 16) {
        unsigned p[16];
#pragma unroll
        for (int k = 0; k < 16; ++k) {
            int o = __shfl(voff, j + k, 64);
            p[k] = *(const unsigned*)(base + (size_t)(unsigned)o);
        }
#pragma unroll
        for (int k = 0; k < 16; ++k) {
            f32x2 lo = __builtin_amdgcn_cvt_pk_f32_fp8(p[k], false);
            f32x2 hi = __builtin_amdgcn_cvt_pk_f32_fp8(p[k], true);
            a0 += lo.x; a1 += lo.y; a2 += hi.x; a3 += hi.y;
        }
    }
    for (; j + 8 <= n; j += 8) {
        unsigned p[8];
#pragma unroll
        for (int k = 0; k < 8; ++k) {
            int o = __shfl(voff, j + k, 64);
            p[k] = *(const unsigned*)(base + (size_t)(unsigned)o);
        }
#pragma unroll
        for (int k = 0; k < 8; ++k) {
            f32x2 lo = __builtin_amdgcn_cvt_pk_f32_fp8(p[k], false);
            f32x2 hi = __builtin_amdgcn_cvt_pk_f32_fp8(p[k], true);
            a0 += lo.x; a1 += lo.y; a2 += hi.x; a3 += hi.y;
        }
    }
    for (; j < n; ++j) {
        int o = __shfl(voff, j, 64);
        unsigned p = *(const unsigned*)(base + (size_t)(unsigned)o);
        f32x2 lo = __builtin_amdgcn_cvt_pk_f32_fp8(p, false);
        f32x2 hi = __builtin_amdgcn_cvt_pk_f32_fp8(p, true);
        a0 += lo.x; a1 += lo.y; a2 += hi.x; a3 += hi.y;
    }
    for (int i = b + 64; i < e; ++i) {
        unsigned p = *(const unsigned*)(base + ((size_t)csr[i] << 8));
        f32x2 lo = __builtin_amdgcn_cvt_pk_f32_fp8(p, false);
        f32x2 hi = __builtin_amdgcn_cvt_pk_f32_fp8(p, true);
        a0 += lo.x; a1 += lo.y; a2 += hi.x; a3 += hi.y;
    }
    float s = sIn[w];
    ushort4 o4;
    o4.x = f2bf(a0 * s); o4.y = f2bf(a1 * s);
    o4.z = f2bf(a2 * s); o4.w = f2bf(a3 * s);
    *(ushort4*)(out + (size_t)w * 256 + lane * 4) = o4;
}

__global__ __launch_bounds__(256) void agg_softmax_f8(const unsigned char* __restrict__ F,
        const int* __restrict__ csr, const int* __restrict__ roff,
        const float* __restrict__ sIn, const float* __restrict__ bias,
        float* __restrict__ outh, ushort* __restrict__ outb, int N) {
    int w = blockIdx.x * 4 + (threadIdx.x >> 6);
    if (w >= N) return;
    int lane = threadIdx.x & 63;
    int b = roff[w], e = roff[w + 1];
    int deg = e - b;
    int n = deg < 64 ? deg : 64;
    float a0 = 0.f, a1 = 0.f;
    const char* base = (const char*)F + lane * 2;
    int voff = 0;
    if (n > 0) voff = csr[b + (lane < n ? lane : n - 1)] << 7;  // 128B rows
    int j = 0;
    for (; j + 16 <= n; j += 16) {
        unsigned p[16];
#pragma unroll
        for (int k = 0; k < 16; ++k) {
            int o = __shfl(voff, j + k, 64);
            p[k] = *(const ushort*)(base + (size_t)(unsigned)o);
        }
#pragma unroll
        for (int k = 0; k < 16; ++k) {
            f32x2 d = __builtin_amdgcn_cvt_pk_f32_fp8(p[k], false);
            a0 += d.x; a1 += d.y;
        }
    }
    for (; j + 8 <= n; j += 8) {
        unsigned p[8];
#pragma unroll
        for (int k = 0; k < 8; ++k) {
            int o = __shfl(voff, j + k, 64);
            p[k] = *(const ushort*)(base + (size_t)(unsigned)o);
        }
#pragma unroll
        for (int k = 0; k < 8; ++k) {
            f32x2 d = __builtin_amdgcn_cvt_pk_f32_fp8(p[k], false);
            a0 += d.x; a1 += d.y;
        }
    }
    for (; j < n; ++j) {
        int o = __shfl(voff, j, 64);
        unsigned p = *(const ushort*)(base + (size_t)(unsigned)o);
        f32x2 d = __builtin_amdgcn_cvt_pk_f32_fp8(p, false);
        a0 += d.x; a1 += d.y;
    }
    for (int i = b + 64; i < e; ++i) {
        unsigned p = *(const ushort*)(base + ((size_t)csr[i] << 7));
        f32x2 d = __builtin_amdgcn_cvt_pk_f32_fp8(p, false);
        a0 += d.x; a1 += d.y;
    }
    float s = sIn[w];
    float2 bb = *(const float2*)(bias + lane * 2);
    float l0 = a0 * s + bb.x, l1 = a1 * s + bb.y;
    float m = fmaxf(l0, l1);
    for (int o = 32; o; o >>= 1) m = fmaxf(m, __shfl_xor(m, o, 64));
    float e0 = __expf(l0 - m), e1 = __expf(l1 - m);
    float sm = e0 + e1;
    for (int o = 32; o; o >>= 1) sm += __shfl_xor(sm, o, 64);
    float inv = 1.f / sm;
    float r0 = e0 * inv, r1 = e1 * inv;
    float2 fo; fo.x = r0; fo.y = r1;
    *(float2*)(outh + (size_t)w * 128 + lane * 2) = fo;
    ushort2 o2; o2.x = f2bf(r0); o2.y = f2bf(r1);
    *(ushort2*)(outb + (size_t)w * 128 + lane * 2) = o2;
}

// ---------- GEMM v3: conflict-free [slot][col] LDS layout, 8 waves ----------
// MODE 0: tanh(acc+bias)*(rowscale?:1) -> bf16 | 1: acc -> bf16
// MODE 3: row_softmax(acc+bias) -> fp32 (Nn==128) | 4: tanh*rowscale -> fp8 | 5: acc -> fp8
template <int MODE, int K>
__global__ __launch_bounds__(512, 4) void gemm3(
        const ushort* __restrict__ A, const ushort* __restrict__ Wt,
        const float* __restrict__ bias, const float* __restrict__ rowscale,
        void* __restrict__ out, int M, int Nn) {
    constexpr int KS = K / 32;          // mfma K-steps (= staged chunks per wave)
    __shared__ ushort ldsW[(K / 8) * 1024];   // K/8 slots x 128 cols x 16B

    const int tid = threadIdx.x;
    const int lane = tid & 63;
    const int wid = tid >> 6;           // 0..7
    const int nby = Nn >> 7;
    const int bx = (int)blockIdx.x / nby;
    const int by = (int)blockIdx.x - bx * nby;
    const int rowbase = bx * 128;
    const int colbase = by * 128;

    // stage: chunk c (1KB) = slot s=c>>1, col half h=c&1; lane covers col h*64+lane
#pragma unroll
    for (int it = 0; it < KS; ++it) {
        int c = wid * KS + it;
        int s = c >> 1, h = c & 1;
        async16(Wt + (size_t)(colbase + h * 64 + lane) * K + s * 8,
                (char*)ldsW + c * 1024);
    }

    // A fragments direct from global (wave's 16 rows; 64B/row per ks step)
    const int l15 = lane & 15, l4 = lane >> 4;
    short8 a[KS];
    {
        int grow = rowbase + wid * 16 + l15;
        if (grow > M - 1) grow = M - 1;
        const ushort* ap = A + (size_t)grow * K + l4 * 8;
#pragma unroll
        for (int ks = 0; ks < KS; ++ks)
            a[ks] = *(const short8*)(ap + ks * 32);
    }

    f32x4 acc[8];
#pragma unroll
    for (int j = 0; j < 8; ++j) acc[j] = (f32x4){0.f, 0.f, 0.f, 0.f};

    __syncthreads();

#pragma unroll
    for (int ks = 0; ks < KS; ++ks) {
        const ushort* bp = &ldsW[(ks * 4 + l4) * 1024 + l15 * 8];
#pragma unroll
        for (int ct = 0; ct < 8; ++ct) {
            short8 b = *(const short8*)(bp + ct * 128);
            acc[ct] = __builtin_amdgcn_mfma_f32_16x16x32_bf16(a[ks], b, acc[ct], 0, 0, 0);
        }
    }

    // epilogue (wave owns rows rowbase+wid*16 .. +15, cols colbase .. +127)
    float bv[8];
#pragma unroll
    for (int ct = 0; ct < 8; ++ct)
        bv[ct] = (MODE != 1 && MODE != 5 && bias) ? bias[colbase + ct * 16 + l15] : 0.f;

    if (MODE == 4 || MODE == 5) {
#pragma unroll
        for (int rg = 0; rg < 4; ++rg) {
            int row = rowbase + wid * 16 + l4 * 4 + rg;
            if (row >= M) continue;            // row uniform over shfl pair
            float sc = (MODE == 4 && rowscale) ? rowscale[row] : 1.f;
#pragma unroll
            for (int ct = 0; ct < 8; ++ct) {
                float v = acc[ct][rg] + bv[ct];
                if (MODE == 4) v = fast_tanh(v) * sc;
                float vp = __shfl_xor(v, 1, 64);   // partner col (l15^1)
                if ((l15 & 1) == 0) {
                    int pk = __builtin_amdgcn_cvt_pk_fp8_f32(v, vp, 0, false);
                    *(ushort*)((char*)out + (size_t)row * Nn + colbase + ct * 16 + l15)
                        = (ushort)(pk & 0xFFFF);
                }
            }
        }
    } else if (MODE != 3) {
#pragma unroll
        for (int rg = 0; rg < 4; ++rg) {
            int row = rowbase + wid * 16 + l4 * 4 + rg;
            if (row >= M) continue;
            float sc = 1.f;
            if (MODE == 0 && rowscale) sc = rowscale[row];
#pragma unroll
            for (int ct = 0; ct < 8; ++ct) {
                int col = colbase + ct * 16 + l15;
                float v = acc[ct][rg] + bv[ct];
                if (MODE == 0) v = fast_tanh(v) * sc;
                ((ushort*)out)[(size_t)row * Nn + col] = f2bf(v);
            }
        }
    } else {
        // wave-local row softmax (row's 128 cols live in 16 lanes x 8 ct)
#pragma unroll
        for (int rg = 0; rg < 4; ++rg) {
            int row = rowbase + wid * 16 + l4 * 4 + rg;
            float m = acc[0][rg] + bv[0];
#pragma unroll
            for (int ct = 1; ct < 8; ++ct) m = fmaxf(m, acc[ct][rg] + bv[ct]);
            m = fmaxf(m, __shfl_xor(m, 1, 64));
            m = fmaxf(m, __shfl_xor(m, 2, 64));
            m = fmaxf(m, __shfl_xor(m, 4, 64));
            m = fmaxf(m, __shfl_xor(m, 8, 64));
            float ev[8], s = 0.f;
#pragma unroll
            for (int ct = 0; ct < 8; ++ct) {
                ev[ct] = __expf(acc[ct][rg] + bv[ct] - m);
                s += ev[ct];
            }
            s += __shfl_xor(s, 1, 64);
            s += __shfl_xor(s, 2, 64);
            s += __shfl_xor(s, 4, 64);
            s += __shfl_xor(s, 8, 64);
            float inv = 1.f / s;
            if (row < M) {
#pragma unroll
                for (int ct = 0; ct < 8; ++ct) {
                    int col = colbase + ct * 16 + l15;
                    ((float*)out)[(size_t)row * Nn + col] = ev[ct] * inv;
                }
            }
        }
    }
}

// ---------- launch ----------
extern "C" void kernel_launch(void* const* d_in, const int* in_sizes, int n_in,
                              void* d_out, int out_size, void* d_ws, size_t ws_size,
                              hipStream_t stream) {
    (void)n_in; (void)out_size; (void)ws_size;
    const float* in_feat = (const float*)d_in[0];
    const int*   src     = (const int*)d_in[1];
    const int*   dstp    = (const int*)d_in[2];
    const float* Wc0 = (const float*)d_in[3];  const float* bc0 = (const float*)d_in[4];
    const float* Wc1 = (const float*)d_in[5];  const float* bc1 = (const float*)d_in[6];
    const float* Wc2 = (const float*)d_in[7];  const float* bc2 = (const float*)d_in[8];
    const float* Wr0 = (const float*)d_in[9];  const float* br0 = (const float*)d_in[10];
    const float* Wr1 = (const float*)d_in[11]; const float* br1 = (const float*)d_in[12];
    const float* Wr2 = (const float*)d_in[13]; const float* br2 = (const float*)d_in[14];

    const int N = in_sizes[0] / 128;
    const int E = in_sizes[1];
    const int numBuckets = (N + ((1 << BSHIFT) - 1)) >> BSHIFT;

    char* ws = (char*)d_ws;
    size_t off = 0;
    auto alloc = [&](size_t bytes) -> char* {
        char* p = ws + off;
        off += (bytes + 255) & ~(size_t)255;
        return p;
    };
    char* S1 = alloc((size_t)N * 256 * 2);
    char* S2 = alloc((size_t)N * 256 * 2);
    int* csr    = (int*)alloc((size_t)E * 4);
    int* roff   = (int*)alloc((size_t)(N + 1) * 4);
    int* sbuf   = (int*)alloc((size_t)E * 4);
    float* sOut = (float*)alloc((size_t)N * 4);
    float* sIn  = (float*)alloc((size_t)N * 4);
    ushort* Wt  = (ushort*)alloc(262144 * 2);
    int* gbc        = (int*)alloc(512 * 4);
    int* bucketBase = (int*)alloc(257 * 4);
    int* pairCursor = (int*)alloc(256 * 4);
    int* srcBase    = (int*)alloc(257 * 4);
    int* srcCursor  = (int*)alloc(256 * 4);
    uint2* pairs = (uint2*)S2;

    hipMemsetAsync(gbc, 0, 512 * 4, stream);

    int nblk = (E + CCHUNK - 1) / CCHUNK;
    bucket_count<<<nblk, 256, 0, stream>>>(src, dstp, gbc, E);
    scan_buckets<<<1, 256, 0, stream>>>(gbc, bucketBase, pairCursor, srcBase, srcCursor,
                                        roff, N, E);
    part_scatter<<<nblk, 256, 0, stream>>>(src, dstp, pairCursor, srcCursor, pairs, sbuf, E);
    build_bucket<<<numBuckets, 1024, 0, stream>>>(pairs, bucketBase, roff, sIn, csr, N);
    src_count<<<numBuckets, 256, 0, stream>>>(sbuf, srcBase, sOut, N);

    convw<<<262144 / 256, 256, 0, stream>>>(Wc0, Wc1, Wc2, Wr0, Wr1, Wr2, Wt);

    // in_feat -> fp8 (128B rows) in S1
    unsigned char* Xf8 = (unsigned char*)S1;
    prescale<<<(N * 32 + 255) / 256, 256, 0, stream>>>(in_feat, sOut, Xf8, N * 32);

    int aggGrid = (N + 3) / 4;
    int nrb = (N + 127) / 128;   // row blocks

    ushort* A0 = (ushort*)S2;
    agg128f8<<<aggGrid, 256, 0, stream>>>(Xf8, csr, roff, sIn, A0, N);
    // conv1 activation -> fp8 (256B rows) for the heavy gather
    unsigned char* B1f8 = (unsigned char*)S1;
    gemm3<4, 128><<<nrb * 2, 512, 0, stream>>>(A0, Wt, bc0, sOut, B1f8, N, 256);
    ushort* A1 = (ushort*)S2;
    agg256f8<<<aggGrid, 256, 0, stream>>>(B1f8, csr, roff, sIn, A1, N);
    ushort* B2 = (ushort*)S1;
    gemm3<0, 256><<<nrb * 2, 512, 0, stream>>>(A1, Wt + 32768, bc1, sOut, B2, N, 256);
    // conv3 pre-agg logits -> fp8 (128B rows)
    unsigned char* T3f8 = (unsigned char*)S2;
    gemm3<5, 256><<<nrb, 512, 0, stream>>>(B2, Wt + 98304, nullptr, nullptr, T3f8, N, 128);
    float* outh = (float*)d_out;
    ushort* Hbf = (ushort*)S1;
    agg_softmax_f8<<<aggGrid, 256, 0, stream>>>(T3f8, csr, roff, sIn, bc2, outh, Hbf, N);
    ushort* R1 = (ushort*)S2;
    gemm3<0, 128><<<nrb * 2, 512, 0, stream>>>(Hbf, Wt + 131072, br0, nullptr, R1, N, 256);
    ushort* R2 = (ushort*)S1;
    gemm3<0, 256><<<nrb * 2, 512, 0, stream>>>(R1, Wt + 163840, br1, nullptr, R2, N, 256);
    gemm3<3, 256><<<nrb, 512, 0, stream>>>(R2, Wt + 229376, br2, nullptr,
                                           outh + (size_t)N * 128, N, 128);
}